// Round 6
// baseline (322.813 us; speedup 1.0000x reference)
//
#include <hip/hip_runtime.h>
#include <hip/hip_bf16.h>
#include <stdint.h>

// Problem constants
#define B_SZ 16384
#define D_SZ 1024
#define H1_SZ 512
#define H2_SZ 256
#define T_SZ 3
#define ESH 2
#define NE 8  // 2 shared + 3 tasks * 2 specific

typedef __bf16 bf16x8 __attribute__((ext_vector_type(8)));
typedef float f32x4 __attribute__((ext_vector_type(4)));
typedef unsigned short u16;
typedef u16 u16x8 __attribute__((ext_vector_type(8)));

__device__ __forceinline__ u16 f2bf(float f) {
  union { float f; uint32_t u; } v; v.f = f;
  uint32_t u = v.u;
  uint32_t r = (u + 0x7FFFu + ((u >> 16) & 1u)) >> 16;  // RNE
  return (u16)r;
}
__device__ __forceinline__ float bf2f(u16 b) {
  union { uint32_t u; float f; } v; v.u = ((uint32_t)b) << 16;
  return v.f;
}

__device__ __forceinline__ void gload16(const u16* src, u16* dst_lds) {
  __builtin_amdgcn_global_load_lds(
      (const __attribute__((address_space(1))) void*)src,
      (__attribute__((address_space(3))) void*)dst_lds, 16, 0, 0);
}

// ------- merged transpose-cast: W1 jobs (z=0..7) and W2 jobs (z=8..15) -------
// [e][K][N] f32 -> [e][N][K] bf16
__global__ __launch_bounds__(256) void transpose_cast_all(
    const float* __restrict__ sW1, const float* __restrict__ pW1,
    const float* __restrict__ sW2, const float* __restrict__ pW2,
    u16* __restrict__ w1t, u16* __restrict__ w2t) {
  __shared__ float tile[32][33];
  const int z = blockIdx.z;
  int K, N;
  const float* s;
  u16* d;
  if (z < 8) {
    K = 1024; N = 512;
    s = (z < 2) ? (sW1 + (size_t)z * K * N) : (pW1 + (size_t)(z - 2) * K * N);
    d = w1t + (size_t)z * K * N;
  } else {
    K = 512; N = 256;
    const int e = z - 8;
    if (blockIdx.x >= 8 || blockIdx.y >= 16) return;
    s = (e < 2) ? (sW2 + (size_t)e * K * N) : (pW2 + (size_t)(e - 2) * K * N);
    d = w2t + (size_t)e * K * N;
  }
  int n0 = blockIdx.x * 32, k0 = blockIdx.y * 32;
  int tx = threadIdx.x, ty = threadIdx.y;
#pragma unroll
  for (int i = ty; i < 32; i += 8)
    tile[i][tx] = s[(size_t)(k0 + i) * N + n0 + tx];
  __syncthreads();
#pragma unroll
  for (int i = ty; i < 32; i += 8)
    d[(size_t)(n0 + i) * K + k0 + tx] = f2bf(tile[tx][i]);
}

// ---- gates + cast: gts = softmax(x @ gate_W + gate_b); xb = bf16(x) ----
__global__ __launch_bounds__(256) void gates_cast_kernel(
    const float* __restrict__ x, const float* __restrict__ gW,
    const float* __restrict__ gb, float* __restrict__ gates,
    u16* __restrict__ xb) {
  __shared__ float gw[12][1024];
  const int tid = threadIdx.x;
  for (int i = tid; i < 12 * 1024; i += 256) {
    int tg = i >> 10, k = i & 1023;
    gw[tg][k] = gW[(size_t)(tg >> 2) * 4096 + (size_t)k * 4 + (tg & 3)];
  }
  __syncthreads();
  const int wid = tid >> 6, lane = tid & 63;
  const size_t b = (size_t)blockIdx.x * 4 + wid;
  const float* xr = x + b * 1024;
  u16* xbr = xb + b * 1024;
  float acc[12] = {};
  for (int kk = 0; kk < 16; ++kk) {
    float xv = xr[kk * 64 + lane];
    xbr[kk * 64 + lane] = f2bf(xv);
#pragma unroll
    for (int t = 0; t < 12; ++t) acc[t] += xv * gw[t][kk * 64 + lane];
  }
#pragma unroll
  for (int off = 32; off >= 1; off >>= 1)
#pragma unroll
    for (int t = 0; t < 12; ++t) acc[t] += __shfl_xor(acc[t], off);
  if (lane == 0) {
    float* gr = gates + b * 12;
#pragma unroll
    for (int t = 0; t < 3; ++t) {
      float l0 = acc[t * 4 + 0] + gb[t * 4 + 0];
      float l1 = acc[t * 4 + 1] + gb[t * 4 + 1];
      float l2 = acc[t * 4 + 2] + gb[t * 4 + 2];
      float l3 = acc[t * 4 + 3] + gb[t * 4 + 3];
      float mx = fmaxf(fmaxf(l0, l1), fmaxf(l2, l3));
      float e0 = __expf(l0 - mx), e1 = __expf(l1 - mx);
      float e2 = __expf(l2 - mx), e3 = __expf(l3 - mx);
      float inv = 1.f / (e0 + e1 + e2 + e3);
      gr[t * 4 + 0] = e0 * inv; gr[t * 4 + 1] = e1 * inv;
      gr[t * 4 + 2] = e2 * inv; gr[t * 4 + 3] = e3 * inv;
    }
  }
}

// ===== layer-1: 128x256 MFMA GEMM, BK=32, 3-slot ring, 2 blocks/CU (R5) =====
__global__ __launch_bounds__(256, 2) void gemm_ring3(
    const u16* __restrict__ A, size_t strideAe,
    const u16* __restrict__ Bt,
    const float* __restrict__ bias_sh, const float* __restrict__ bias_sp,
    u16* __restrict__ C, int M, int N, int K, int ntn_sh) {
  __shared__ __align__(16) u16 lds[3 * 12288];  // 72 KB
  const int tid = threadIdx.x;
  const int wid = tid >> 6, lane = tid & 63;
  const int fr = lane & 15, fq = lane >> 4;
  const int wc = wid;

  const int bid = blockIdx.x;
  const int e = bid & 7;
  const int r = bid >> 3;
  const int mtile = r >> ntn_sh;
  const int ntile = r & ((1 << ntn_sh) - 1);
  const int m0 = mtile * 128, n0 = ntile * 256;

  const u16* Ae = A + (size_t)e * strideAe;
  const u16* Be = Bt + (size_t)e * (size_t)N * K;
  const int NT = K >> 5;

  const u16* pA[2];
  const u16* pB[4];
#pragma unroll
  for (int p = 0; p < 2; ++p) {
    int c = p * 256 + tid, row = c >> 2, sl = (c & 3) ^ ((row >> 1) & 3);
    pA[p] = Ae + (size_t)(m0 + row) * K + sl * 8;
  }
#pragma unroll
  for (int p = 0; p < 4; ++p) {
    int c = p * 256 + tid, row = c >> 2, sl = (c & 3) ^ ((row >> 1) & 3);
    pB[p] = Be + (size_t)(n0 + row) * K + sl * 8;
  }
  const int wdst = wid * 512;

  int offA[8], offB[4];
#pragma unroll
  for (int m = 0; m < 8; ++m) {
    int rr = m * 16 + fr;
    offA[m] = rr * 32 + ((fq ^ ((rr >> 1) & 3)) * 8);
  }
#pragma unroll
  for (int n = 0; n < 4; ++n) {
    int cg = wc * 64 + n * 16 + fr;
    offB[n] = 4096 + cg * 32 + ((fq ^ ((cg >> 1) & 3)) * 8);
  }

  f32x4 acc[8][4] = {};

#define STAGE(t, sb) do {                                             \
    gload16(pA[0] + (size_t)(t) * 32, &lds[(sb) + wdst]);             \
    gload16(pA[1] + (size_t)(t) * 32, &lds[(sb) + 2048 + wdst]);      \
    gload16(pB[0] + (size_t)(t) * 32, &lds[(sb) + 4096 + wdst]);      \
    gload16(pB[1] + (size_t)(t) * 32, &lds[(sb) + 6144 + wdst]);      \
    gload16(pB[2] + (size_t)(t) * 32, &lds[(sb) + 8192 + wdst]);      \
    gload16(pB[3] + (size_t)(t) * 32, &lds[(sb) + 10240 + wdst]); } while (0)

  STAGE(0, 0);
  STAGE(1, 12288);
  asm volatile("s_waitcnt vmcnt(6)");
  __builtin_amdgcn_s_barrier();
  __builtin_amdgcn_sched_barrier(0);

  int sb_cur = 0;
  for (int t = 0; t < NT; ++t) {
    const u16* sl = &lds[sb_cur];
    bf16x8 av[8], bv[4];
#pragma unroll
    for (int m = 0; m < 8; ++m) av[m] = *(const bf16x8*)&sl[offA[m]];
#pragma unroll
    for (int n = 0; n < 4; ++n) bv[n] = *(const bf16x8*)&sl[offB[n]];
    if (t + 2 < NT) {
      int sb_n2 = sb_cur + 2 * 12288;
      if (sb_n2 >= 36864) sb_n2 -= 36864;
      STAGE(t + 2, sb_n2);
    }
    __builtin_amdgcn_s_setprio(1);
#pragma unroll
    for (int m = 0; m < 8; ++m)
#pragma unroll
      for (int n = 0; n < 4; ++n)
        acc[m][n] = __builtin_amdgcn_mfma_f32_16x16x32_bf16(av[m], bv[n], acc[m][n], 0, 0, 0);
    __builtin_amdgcn_s_setprio(0);
    if (t + 2 < NT)      asm volatile("s_waitcnt vmcnt(6)");
    else if (t + 1 < NT) asm volatile("s_waitcnt vmcnt(0)");
    __builtin_amdgcn_s_barrier();
    __builtin_amdgcn_sched_barrier(0);
    sb_cur += 12288;
    if (sb_cur >= 36864) sb_cur = 0;
  }
#undef STAGE

  const float* bias = (e < ESH) ? (bias_sh + (size_t)e * N)
                                : (bias_sp + (size_t)(e - ESH) * N);
  u16* Ce = C + (size_t)e * (size_t)M * N;
  float bb[4];
#pragma unroll
  for (int n = 0; n < 4; ++n) bb[n] = bias[n0 + wc * 64 + n * 16 + fr];

#pragma unroll
  for (int m = 0; m < 8; ++m) {
#pragma unroll
    for (int n = 0; n < 4; ++n) {
      const int col = wc * 64 + n * 16 + fr;
      f32x4 a = acc[m][n];
#pragma unroll
      for (int rr = 0; rr < 4; ++rr) {
        float v = a[rr] + bb[n];
        v = v > 0.f ? v : 0.f;
        lds[(m * 16 + fq * 4 + rr) * 264 + col] = f2bf(v);
      }
    }
  }
  __builtin_amdgcn_s_barrier();
  const int cc = (tid & 31) * 8;
  const int rr8 = tid >> 5;
#pragma unroll
  for (int pass = 0; pass < 16; ++pass) {
    const int lr = pass * 8 + rr8;
    u16x8 vv = *(const u16x8*)&lds[lr * 264 + cc];
    *(u16x8*)&Ce[(size_t)(m0 + lr) * N + n0 + cc] = vv;
  }
}

// ===== fused layer-2 GEMM + gate-combine =====
// Block: 64 rows x 128 cols, 256 thr = 4 waves (1M x 4N), wave tile 64x32.
// Loops over 8 experts x 16 K-tiles (flat 128-tile loop, 3-slot ring, vmcnt(3)).
// y2 stays in regs (f32); per expert: relu+bias, scale by gates, accumulate
// into outacc[3][4][2][4] (96 f32); direct f32 store to out. No y2 buffer.
__global__ __launch_bounds__(256, 2) void fused_l2c(
    const u16* __restrict__ y1, const u16* __restrict__ w2t,
    const float* __restrict__ sb2, const float* __restrict__ pb2,
    const float* __restrict__ gts, float* __restrict__ out) {
  __shared__ __align__(16) u16 ring[3 * 6144];  // 36 KB (A 2048 + B 4096 per slot)
  __shared__ float gl[64 * 12];                 // gates for block rows
  __shared__ float bl[8 * 128];                 // bias per expert per col
  const int tid = threadIdx.x;
  const int wid = tid >> 6, lane = tid & 63;
  const int fr = lane & 15, fq = lane >> 4;

  const int bid = blockIdx.x;
  const int bm = bid >> 1, bn = bid & 1;
  const int m0 = bm * 64;
  const int ncol0 = bn * 128;

  // preload gates + biases to LDS
  for (int i = tid; i < 768; i += 256)
    gl[i] = gts[(size_t)(m0 + i / 12) * 12 + (i % 12)];
  for (int i = tid; i < 1024; i += 256) {
    int e = i >> 7, c = i & 127;
    bl[i] = (e < 2) ? sb2[e * 256 + ncol0 + c] : pb2[(e - 2) * 256 + ncol0 + c];
  }

  // staging sources (pre-swizzled)
  const int cA = tid, rowA = cA >> 2, slA = (cA & 3) ^ ((rowA >> 1) & 3);
  const u16* pAf = y1 + (size_t)(m0 + rowA) * 512 + slA * 8;
  const u16* pBf[2];
#pragma unroll
  for (int p = 0; p < 2; ++p) {
    int c = p * 256 + tid, row = c >> 2, sl = (c & 3) ^ ((row >> 1) & 3);
    pBf[p] = w2t + (size_t)(ncol0 + row) * 512 + sl * 8;
  }
  const int wdst = wid * 512;

  // ds_read offsets
  int offA[4], offB[2];
#pragma unroll
  for (int m = 0; m < 4; ++m) {
    int rr = m * 16 + fr;
    offA[m] = rr * 32 + ((fq ^ ((rr >> 1) & 3)) * 8);
  }
#pragma unroll
  for (int n = 0; n < 2; ++n) {
    int cg = wid * 32 + n * 16 + fr;
    offB[n] = 2048 + cg * 32 + ((fq ^ ((cg >> 1) & 3)) * 8);
  }

  f32x4 acc[4][2] = {};
  float oa[3][4][2][4] = {};

  // STAGE flat tile g: e=g>>4, kt=g&15
#define STAGE2(g, sb) do {                                                      \
    const size_t eo = (size_t)((g) >> 4);                                       \
    const int ko = ((g) & 15) * 32;                                             \
    gload16(pAf + eo * ((size_t)B_SZ * 512) + ko, &ring[(sb) + wdst]);          \
    gload16(pBf[0] + eo * 131072 + ko, &ring[(sb) + 2048 + wdst]);              \
    gload16(pBf[1] + eo * 131072 + ko, &ring[(sb) + 4096 + wdst]); } while (0)

  STAGE2(0, 0);
  STAGE2(1, 6144);
  __syncthreads();  // covers gl/bl writes; drains prefetch once (prologue only)

  int sb_cur = 0;
  for (int g = 0; g < 128; ++g) {
    const u16* sl = &ring[sb_cur];
    bf16x8 av[4], bv[2];
#pragma unroll
    for (int m = 0; m < 4; ++m) av[m] = *(const bf16x8*)&sl[offA[m]];
#pragma unroll
    for (int n = 0; n < 2; ++n) bv[n] = *(const bf16x8*)&sl[offB[n]];
    if (g + 2 < 128) {
      int sb_n2 = sb_cur + 2 * 6144;
      if (sb_n2 >= 18432) sb_n2 -= 18432;
      STAGE2(g + 2, sb_n2);
    }
    __builtin_amdgcn_s_setprio(1);
#pragma unroll
    for (int m = 0; m < 4; ++m)
#pragma unroll
      for (int n = 0; n < 2; ++n)
        acc[m][n] = __builtin_amdgcn_mfma_f32_16x16x32_bf16(av[m], bv[n], acc[m][n], 0, 0, 0);
    __builtin_amdgcn_s_setprio(0);
    if (g + 2 < 128)      asm volatile("s_waitcnt vmcnt(3)");
    else if (g + 1 < 128) asm volatile("s_waitcnt vmcnt(0)");
    __builtin_amdgcn_s_barrier();
    __builtin_amdgcn_sched_barrier(0);
    sb_cur += 6144;
    if (sb_cur >= 18432) sb_cur = 0;

    if ((g & 15) == 15) {
      // expert e finished: relu+bias, gate-weighted accumulate, reset acc
      const int e = g >> 4;
#pragma unroll
      for (int m = 0; m < 4; ++m) {
#pragma unroll
        for (int rr = 0; rr < 4; ++rr) {
          const int row = m * 16 + fq * 4 + rr;
          if (e < 2) {
            const float g0 = gl[row * 12 + 0 * 4 + e];
            const float g1 = gl[row * 12 + 1 * 4 + e];
            const float g2 = gl[row * 12 + 2 * 4 + e];
#pragma unroll
            for (int n = 0; n < 2; ++n) {
              const int col = wid * 32 + n * 16 + fr;
              float v = acc[m][n][rr] + bl[e * 128 + col];
              v = v > 0.f ? v : 0.f;
              oa[0][m][n][rr] += g0 * v;
              oa[1][m][n][rr] += g1 * v;
              oa[2][m][n][rr] += g2 * v;
            }
          } else {
            const int t = (e - 2) >> 1, gi = 2 + ((e - 2) & 1);
            const float gv = gl[row * 12 + t * 4 + gi];
#pragma unroll
            for (int n = 0; n < 2; ++n) {
              const int col = wid * 32 + n * 16 + fr;
              float v = acc[m][n][rr] + bl[e * 128 + col];
              v = v > 0.f ? v : 0.f;
              if (t == 0) oa[0][m][n][rr] += gv * v;
              else if (t == 1) oa[1][m][n][rr] += gv * v;
              else oa[2][m][n][rr] += gv * v;
            }
          }
#pragma unroll
          for (int n = 0; n < 2; ++n) acc[m][n][rr] = 0.f;
        }
      }
    }
  }
#undef STAGE2

  // write out [B][3][256] f32
#pragma unroll
  for (int t = 0; t < 3; ++t)
#pragma unroll
    for (int m = 0; m < 4; ++m)
#pragma unroll
      for (int rr = 0; rr < 4; ++rr) {
        const int row = m * 16 + fq * 4 + rr;
#pragma unroll
        for (int n = 0; n < 2; ++n) {
          const int col = wid * 32 + n * 16 + fr;
          out[(size_t)(m0 + row) * 768 + t * 256 + ncol0 + col] = oa[t][m][n][rr];
        }
      }
}

extern "C" void kernel_launch(void* const* d_in, const int* in_sizes, int n_in,
                              void* d_out, int out_size, void* d_ws, size_t ws_size,
                              hipStream_t stream) {
  (void)in_sizes; (void)n_in; (void)out_size; (void)ws_size;
  const float* x   = (const float*)d_in[0];
  const float* sW1 = (const float*)d_in[1];
  const float* sb1 = (const float*)d_in[2];
  const float* sW2 = (const float*)d_in[3];
  const float* sb2 = (const float*)d_in[4];
  const float* pW1 = (const float*)d_in[5];
  const float* pb1 = (const float*)d_in[6];
  const float* pW2 = (const float*)d_in[7];
  const float* pb2 = (const float*)d_in[8];
  const float* gW  = (const float*)d_in[9];
  const float* gb  = (const float*)d_in[10];

  uint8_t* ws = (uint8_t*)d_ws;
  u16* xb    = (u16*)(ws);                        // 33,554,432 B
  u16* w1t   = (u16*)(ws + 33554432);             //  8,388,608 B  [8][512][1024]
  u16* w2t   = (u16*)(ws + 41943040);             //  2,097,152 B  [8][256][512]
  u16* y1    = (u16*)(ws + 44040192);             // 134,217,728 B [8][B][512]
  float* gts = (float*)(ws + 178257920);          //    786,432 B  [B][3][4]

  // 1) all weight transposes in one launch (W1: z=0..7, W2: z=8..15)
  transpose_cast_all<<<dim3(16, 32, 16), dim3(32, 8), 0, stream>>>(
      sW1, pW1, sW2, pW2, w1t, w2t);

  // 2) gates + x-cast fused
  gates_cast_kernel<<<B_SZ / 4, 256, 0, stream>>>(x, gW, gb, gts, xb);

  // 3) layer-1 GEMM: y1[e] = relu(xb @ w1t[e]^T + b1[e])   grid 128*2*8 = 2048
  gemm_ring3<<<(B_SZ / 128) * (512 / 256) * NE, 256, 0, stream>>>(
      xb, 0, w1t, sb1, pb1, y1, B_SZ, 512, 1024, 1);

  // 4) fused layer-2 + combine -> out [B][3][256] f32   grid 256*2 = 512
  fused_l2c<<<(B_SZ / 64) * 2, 256, 0, stream>>>(
      y1, w2t, sb2, pb2, gts, (float*)d_out);
}

// Round 7
// 296.990 us; speedup vs baseline: 1.0869x; 1.0869x over previous
//
#include <hip/hip_runtime.h>
#include <hip/hip_bf16.h>
#include <stdint.h>

// Problem constants
#define B_SZ 16384
#define D_SZ 1024
#define H1_SZ 512
#define H2_SZ 256
#define T_SZ 3
#define ESH 2
#define NE 8  // 2 shared + 3 tasks * 2 specific

typedef __bf16 bf16x8 __attribute__((ext_vector_type(8)));
typedef float f32x4 __attribute__((ext_vector_type(4)));
typedef unsigned short u16;
typedef u16 u16x8 __attribute__((ext_vector_type(8)));

__device__ __forceinline__ u16 f2bf(float f) {
  union { float f; uint32_t u; } v; v.f = f;
  uint32_t u = v.u;
  uint32_t r = (u + 0x7FFFu + ((u >> 16) & 1u)) >> 16;  // RNE
  return (u16)r;
}
__device__ __forceinline__ float bf2f(u16 b) {
  union { uint32_t u; float f; } v; v.u = ((uint32_t)b) << 16;
  return v.f;
}

__device__ __forceinline__ void gload16(const u16* src, u16* dst_lds) {
  __builtin_amdgcn_global_load_lds(
      (const __attribute__((address_space(1))) void*)src,
      (__attribute__((address_space(3))) void*)dst_lds, 16, 0, 0);
}

// ------- merged transpose-cast: W1 jobs (z=0..7) and W2 jobs (z=8..15) -------
// [e][K][N] f32 -> [e][N][K] bf16
__global__ __launch_bounds__(256) void transpose_cast_all(
    const float* __restrict__ sW1, const float* __restrict__ pW1,
    const float* __restrict__ sW2, const float* __restrict__ pW2,
    u16* __restrict__ w1t, u16* __restrict__ w2t) {
  __shared__ float tile[32][33];
  const int z = blockIdx.z;
  int K, N;
  const float* s;
  u16* d;
  if (z < 8) {
    K = 1024; N = 512;
    s = (z < 2) ? (sW1 + (size_t)z * K * N) : (pW1 + (size_t)(z - 2) * K * N);
    d = w1t + (size_t)z * K * N;
  } else {
    K = 512; N = 256;
    const int e = z - 8;
    if (blockIdx.x >= 8 || blockIdx.y >= 16) return;
    s = (e < 2) ? (sW2 + (size_t)e * K * N) : (pW2 + (size_t)(e - 2) * K * N);
    d = w2t + (size_t)e * K * N;
  }
  int n0 = blockIdx.x * 32, k0 = blockIdx.y * 32;
  int tx = threadIdx.x, ty = threadIdx.y;
#pragma unroll
  for (int i = ty; i < 32; i += 8)
    tile[i][tx] = s[(size_t)(k0 + i) * N + n0 + tx];
  __syncthreads();
#pragma unroll
  for (int i = ty; i < 32; i += 8)
    d[(size_t)(n0 + i) * K + k0 + tx] = f2bf(tile[tx][i]);
}

// ---- gates + cast: gts = softmax(x @ gate_W + gate_b); xb = bf16(x) ----
__global__ __launch_bounds__(256) void gates_cast_kernel(
    const float* __restrict__ x, const float* __restrict__ gW,
    const float* __restrict__ gb, float* __restrict__ gates,
    u16* __restrict__ xb) {
  __shared__ float gw[12][1024];
  const int tid = threadIdx.x;
  for (int i = tid; i < 12 * 1024; i += 256) {
    int tg = i >> 10, k = i & 1023;
    gw[tg][k] = gW[(size_t)(tg >> 2) * 4096 + (size_t)k * 4 + (tg & 3)];
  }
  __syncthreads();
  const int wid = tid >> 6, lane = tid & 63;
  const size_t b = (size_t)blockIdx.x * 4 + wid;
  const float* xr = x + b * 1024;
  u16* xbr = xb + b * 1024;
  float acc[12] = {};
  for (int kk = 0; kk < 16; ++kk) {
    float xv = xr[kk * 64 + lane];
    xbr[kk * 64 + lane] = f2bf(xv);
#pragma unroll
    for (int t = 0; t < 12; ++t) acc[t] += xv * gw[t][kk * 64 + lane];
  }
#pragma unroll
  for (int off = 32; off >= 1; off >>= 1)
#pragma unroll
    for (int t = 0; t < 12; ++t) acc[t] += __shfl_xor(acc[t], off);
  if (lane == 0) {
    float* gr = gates + b * 12;
#pragma unroll
    for (int t = 0; t < 3; ++t) {
      float l0 = acc[t * 4 + 0] + gb[t * 4 + 0];
      float l1 = acc[t * 4 + 1] + gb[t * 4 + 1];
      float l2 = acc[t * 4 + 2] + gb[t * 4 + 2];
      float l3 = acc[t * 4 + 3] + gb[t * 4 + 3];
      float mx = fmaxf(fmaxf(l0, l1), fmaxf(l2, l3));
      float e0 = __expf(l0 - mx), e1 = __expf(l1 - mx);
      float e2 = __expf(l2 - mx), e3 = __expf(l3 - mx);
      float inv = 1.f / (e0 + e1 + e2 + e3);
      gr[t * 4 + 0] = e0 * inv; gr[t * 4 + 1] = e1 * inv;
      gr[t * 4 + 2] = e2 * inv; gr[t * 4 + 3] = e3 * inv;
    }
  }
}

// ======== 256x256 MFMA GEMM, BK=32, m201-style 2-phase/tile interleave ========
// C[e] = relu(A[e] @ Bt[e]^T + bias[e]),  A:[M][K] bf16, Bt:[e][N][K] bf16.
// 512 thr = 8 waves (2M x 4N), per-wave 128x64, acc[8][4] (128 AGPR).
// LDS: 4-slot ring x (A[256][32]+B[256][32]) = 128 KB, tile u <-> slot u&3.
// Per tile, 2 phases; each phase: {ds_read subtile | stage one half-tile pair
// of tile t+2 -> s_barrier -> lgkmcnt(0)+sched_barrier -> setprio(1) ->
// 16 pure MFMA -> setprio(0) -> s_barrier}.  Counted vmcnt(4) once per tile
// at P2 (outstanding = t+1's 4 loads + t+2's 4 loads; keep newest 4) — never
// drains to 0 in steady state; exact tail: vmcnt(0) at t=NT-2, none at NT-1.
// Layout/swizzle byte-identical to R5 (proven conflict-free):
// slot' = slot ^ ((row>>1)&3) on BOTH stage-source and ds_read.
__global__ __launch_bounds__(512, 2) void gemm_2ph(
    const u16* __restrict__ A, size_t strideAe,
    const u16* __restrict__ Bt,
    const float* __restrict__ bias_sh, const float* __restrict__ bias_sp,
    u16* __restrict__ C, int M, int N, int K, int ntn_sh) {
  __shared__ __align__(16) u16 lds[4 * 16384];  // 128 KB
  const int tid = threadIdx.x;
  const int wid = tid >> 6, lane = tid & 63;
  const int fr = lane & 15, fq = lane >> 4;
  const int wr = wid >> 2, wc = wid & 3;

  const int bid = blockIdx.x;
  const int e = bid & 7;                    // expert <-> XCD
  const int rest = bid >> 3;
  const int mtile = rest >> ntn_sh;
  const int ntile = rest & ((1 << ntn_sh) - 1);
  const int m0 = mtile * 256, n0 = ntile * 256;

  const u16* Ae = A + (size_t)e * strideAe;
  const u16* Be = Bt + (size_t)e * (size_t)N * K;
  const int NT = K >> 5;  // K-tiles of 32 (>= 4 here: 16 or 32)

  // staging: per half-tile (128 rows x 32 K = 8KB) each thread does 1 gload.
  // row-in-half = tid>>2, slot = tid&3, swizzled source slot = slot^((row>>1)&3)
  const int srow = tid >> 2;
  const int sslot = (tid & 3) ^ ((tid >> 3) & 3);
  const u16* pA[2];
  const u16* pB[2];
#pragma unroll
  for (int h = 0; h < 2; ++h) {
    pA[h] = Ae + (size_t)(m0 + h * 128 + srow) * K + sslot * 8;
    pB[h] = Be + (size_t)(n0 + h * 128 + srow) * K + sslot * 8;
  }
  const int wdst = wid * 512;  // wave-uniform (elems); HW adds lane*16B

  // ds_read element offsets (swizzled); slot layout [A:8192][B:8192]
  int offA[8], offB[4];
#pragma unroll
  for (int m = 0; m < 8; ++m) {
    int rr = wr * 128 + m * 16 + fr;
    offA[m] = rr * 32 + ((fq ^ ((fr >> 1) & 3)) * 8);
  }
#pragma unroll
  for (int n = 0; n < 4; ++n) {
    int cg = wc * 64 + n * 16 + fr;
    offB[n] = 8192 + cg * 32 + ((fq ^ ((fr >> 1) & 3)) * 8);
  }

  f32x4 acc[8][4] = {};

#define STG_A(t) do { const int sbs = ((t) & 3) * 16384;                    \
    gload16(pA[0] + (size_t)(t) * 32, &lds[sbs + wdst]);                    \
    gload16(pA[1] + (size_t)(t) * 32, &lds[sbs + 4096 + wdst]); } while (0)
#define STG_B(t) do { const int sbs = ((t) & 3) * 16384 + 8192;             \
    gload16(pB[0] + (size_t)(t) * 32, &lds[sbs + wdst]);                    \
    gload16(pB[1] + (size_t)(t) * 32, &lds[sbs + 4096 + wdst]); } while (0)

  // prologue: stage tiles 0 and 1 (8 loads); wait tile 0 (keep tile 1 in flight)
  STG_A(0); STG_B(0);
  STG_A(1); STG_B(1);
  asm volatile("s_waitcnt vmcnt(4)");
  __builtin_amdgcn_s_barrier();
  __builtin_amdgcn_sched_barrier(0);

  for (int t = 0; t < NT; ++t) {
    const u16* sl = &lds[(t & 3) * 16384];
    // ---------------- phase 1: rows wr*128+0..63 ----------------
    bf16x8 av[4], bv[4];
#pragma unroll
    for (int m = 0; m < 4; ++m) av[m] = *(const bf16x8*)&sl[offA[m]];
#pragma unroll
    for (int n = 0; n < 4; ++n) bv[n] = *(const bf16x8*)&sl[offB[n]];
    if (t + 2 < NT) STG_A(t + 2);
    __builtin_amdgcn_s_barrier();
    asm volatile("s_waitcnt lgkmcnt(0)");
    __builtin_amdgcn_sched_barrier(0);
    __builtin_amdgcn_s_setprio(1);
#pragma unroll
    for (int m = 0; m < 4; ++m)
#pragma unroll
      for (int n = 0; n < 4; ++n)
        acc[m][n] = __builtin_amdgcn_mfma_f32_16x16x32_bf16(av[m], bv[n], acc[m][n], 0, 0, 0);
    __builtin_amdgcn_s_setprio(0);
    __builtin_amdgcn_s_barrier();
    // ---------------- phase 2: rows wr*128+64..127 ----------------
    bf16x8 aw[4];
#pragma unroll
    for (int m = 0; m < 4; ++m) aw[m] = *(const bf16x8*)&sl[offA[4 + m]];
    if (t + 2 < NT) STG_B(t + 2);
    // counted wait: tile t+1's 4 loads are the oldest; keep t+2's 4 in flight
    if (t + 2 < NT)      asm volatile("s_waitcnt vmcnt(4)");
    else if (t + 1 < NT) asm volatile("s_waitcnt vmcnt(0)");
    __builtin_amdgcn_s_barrier();
    asm volatile("s_waitcnt lgkmcnt(0)");
    __builtin_amdgcn_sched_barrier(0);
    __builtin_amdgcn_s_setprio(1);
#pragma unroll
    for (int m = 0; m < 4; ++m)
#pragma unroll
      for (int n = 0; n < 4; ++n)
        acc[4 + m][n] = __builtin_amdgcn_mfma_f32_16x16x32_bf16(aw[m], bv[n], acc[4 + m][n], 0, 0, 0);
    __builtin_amdgcn_s_setprio(0);
    __builtin_amdgcn_s_barrier();
  }
#undef STG_A
#undef STG_B

  // ---- epilogue: bias+relu -> bf16, coalesced via LDS transpose (2 halves) ----
  const float* bias = (e < ESH) ? (bias_sh + (size_t)e * N)
                                : (bias_sp + (size_t)(e - ESH) * N);
  u16* Ce = C + (size_t)e * (size_t)M * N;
  float bb[4];
#pragma unroll
  for (int n = 0; n < 4; ++n) bb[n] = bias[n0 + wc * 64 + n * 16 + fr];

  const int src = (tid >> 5);            // row-within-pass 0..15
  const int cc = (tid & 31) * 8;         // col chunk of 8
#pragma unroll
  for (int half = 0; half < 2; ++half) {
    if (wr == half) {
#pragma unroll
      for (int m = 0; m < 8; ++m) {
#pragma unroll
        for (int n = 0; n < 4; ++n) {
          const int col = wc * 64 + n * 16 + fr;
          f32x4 a = acc[m][n];
#pragma unroll
          for (int rr = 0; rr < 4; ++rr) {
            float v = a[rr] + bb[n];
            v = v > 0.f ? v : 0.f;
            lds[(m * 16 + fq * 4 + rr) * 264 + col] = f2bf(v);
          }
        }
      }
    }
    __builtin_amdgcn_s_barrier();
#pragma unroll
    for (int pass = 0; pass < 8; ++pass) {
      const int lr = pass * 16 + src;                  // 0..127
      const int gr = m0 + half * 128 + lr;
      u16x8 vv = *(const u16x8*)&lds[lr * 264 + cc];
      *(u16x8*)&Ce[(size_t)gr * N + n0 + cc] = vv;
    }
    __builtin_amdgcn_s_barrier();
  }
}

// ---------------- combine: out[b][t][h] = sum_g gate[b][t][g] * Y2[slot][b][h] ----------------
__global__ __launch_bounds__(256) void combine_kernel(
    const u16* __restrict__ y2, const float* __restrict__ gates,
    float* __restrict__ out) {
  const int tid = threadIdx.x;
  const int rb = tid >> 5;            // row within block (8 rows/block)
  const int hc = (tid & 31) * 8;      // h chunk of 8
  const size_t b = (size_t)blockIdx.x * 8 + rb;
  const float* g = gates + b * 12;
  float acc0[8] = {}, acc1[8] = {}, acc2[8] = {};
#pragma unroll
  for (int e = 0; e < 8; ++e) {
    u16x8 v = *(const u16x8*)&y2[(size_t)e * B_SZ * H2_SZ + b * H2_SZ + hc];
    float f[8];
#pragma unroll
    for (int i = 0; i < 8; ++i) f[i] = bf2f(v[i]);
    if (e < 2) {
      float g0 = g[0 * 4 + e], g1 = g[1 * 4 + e], g2 = g[2 * 4 + e];
#pragma unroll
      for (int i = 0; i < 8; ++i) {
        acc0[i] += g0 * f[i]; acc1[i] += g1 * f[i]; acc2[i] += g2 * f[i];
      }
    } else {
      const int t = (e - 2) >> 1, gi = 2 + ((e - 2) & 1);
      float gv = g[t * 4 + gi];
      float* acc = (t == 0) ? acc0 : (t == 1) ? acc1 : acc2;
#pragma unroll
      for (int i = 0; i < 8; ++i) acc[i] += gv * f[i];
    }
  }
  float* o = out + b * (3 * 256);
  *(float4*)&o[0 * 256 + hc]     = make_float4(acc0[0], acc0[1], acc0[2], acc0[3]);
  *(float4*)&o[0 * 256 + hc + 4] = make_float4(acc0[4], acc0[5], acc0[6], acc0[7]);
  *(float4*)&o[1 * 256 + hc]     = make_float4(acc1[0], acc1[1], acc1[2], acc1[3]);
  *(float4*)&o[1 * 256 + hc + 4] = make_float4(acc1[4], acc1[5], acc1[6], acc1[7]);
  *(float4*)&o[2 * 256 + hc]     = make_float4(acc2[0], acc2[1], acc2[2], acc2[3]);
  *(float4*)&o[2 * 256 + hc + 4] = make_float4(acc2[4], acc2[5], acc2[6], acc2[7]);
}

extern "C" void kernel_launch(void* const* d_in, const int* in_sizes, int n_in,
                              void* d_out, int out_size, void* d_ws, size_t ws_size,
                              hipStream_t stream) {
  (void)in_sizes; (void)n_in; (void)out_size; (void)ws_size;
  const float* x   = (const float*)d_in[0];
  const float* sW1 = (const float*)d_in[1];
  const float* sb1 = (const float*)d_in[2];
  const float* sW2 = (const float*)d_in[3];
  const float* sb2 = (const float*)d_in[4];
  const float* pW1 = (const float*)d_in[5];
  const float* pb1 = (const float*)d_in[6];
  const float* pW2 = (const float*)d_in[7];
  const float* pb2 = (const float*)d_in[8];
  const float* gW  = (const float*)d_in[9];
  const float* gb  = (const float*)d_in[10];

  uint8_t* ws = (uint8_t*)d_ws;
  u16* xb    = (u16*)(ws);                        // 33,554,432 B
  u16* w1t   = (u16*)(ws + 33554432);             //  8,388,608 B  [8][512][1024]
  u16* w2t   = (u16*)(ws + 41943040);             //  2,097,152 B  [8][256][512]
  u16* y1    = (u16*)(ws + 44040192);             // 134,217,728 B [8][B][512]
  u16* y2    = (u16*)(ws + 178257920);            // 67,108,864 B  [8][B][256]
  float* gts = (float*)(ws + 245366784);          //    786,432 B  [B][3][4]

  // 1) all weight transposes in one launch (W1: z=0..7, W2: z=8..15)
  transpose_cast_all<<<dim3(16, 32, 16), dim3(32, 8), 0, stream>>>(
      sW1, pW1, sW2, pW2, w1t, w2t);

  // 2) gates + x-cast fused
  gates_cast_kernel<<<B_SZ / 4, 256, 0, stream>>>(x, gW, gb, gts, xb);

  // 3) layer-1 GEMM: y1[e] = relu(xb @ w1t[e]^T + b1[e])   grid 64*2*8 = 1024
  gemm_2ph<<<(B_SZ / 256) * (512 / 256) * NE, 512, 0, stream>>>(
      xb, 0, w1t, sb1, pb1, y1, B_SZ, 512, 1024, 1);

  // 4) layer-2 GEMM: y2[e] = relu(y1[e] @ w2t[e]^T + b2[e])  grid 64*1*8 = 512
  gemm_2ph<<<(B_SZ / 256) * (256 / 256) * NE, 512, 0, stream>>>(
      y1, (size_t)B_SZ * 512, w2t, sb2, pb2, y2, B_SZ, 256, 512, 0);

  // 5) combine with gates -> out [B][3][256] fp32
  combine_kernel<<<B_SZ / 8, 256, 0, stream>>>(y2, gts, (float*)d_out);
}

// Round 8
// 283.960 us; speedup vs baseline: 1.1368x; 1.0459x over previous
//
#include <hip/hip_runtime.h>
#include <hip/hip_bf16.h>
#include <stdint.h>

// Problem constants
#define B_SZ 16384
#define D_SZ 1024
#define H1_SZ 512
#define H2_SZ 256
#define T_SZ 3
#define ESH 2
#define NE 8  // 2 shared + 3 tasks * 2 specific

typedef __bf16 bf16x8 __attribute__((ext_vector_type(8)));
typedef float f32x4 __attribute__((ext_vector_type(4)));
typedef unsigned short u16;
typedef u16 u16x8 __attribute__((ext_vector_type(8)));

__device__ __forceinline__ u16 f2bf(float f) {
  union { float f; uint32_t u; } v; v.f = f;
  uint32_t u = v.u;
  uint32_t r = (u + 0x7FFFu + ((u >> 16) & 1u)) >> 16;  // RNE
  return (u16)r;
}
__device__ __forceinline__ float bf2f(u16 b) {
  union { uint32_t u; float f; } v; v.u = ((uint32_t)b) << 16;
  return v.f;
}

__device__ __forceinline__ void gload16(const u16* src, u16* dst_lds) {
  __builtin_amdgcn_global_load_lds(
      (const __attribute__((address_space(1))) void*)src,
      (__attribute__((address_space(3))) void*)dst_lds, 16, 0, 0);
}

// ------- merged transpose-cast: W1 jobs (z=0..7) and W2 jobs (z=8..15) -------
// [e][K][N] f32 -> [e][N][K] bf16
__global__ __launch_bounds__(256) void transpose_cast_all(
    const float* __restrict__ sW1, const float* __restrict__ pW1,
    const float* __restrict__ sW2, const float* __restrict__ pW2,
    u16* __restrict__ w1t, u16* __restrict__ w2t) {
  __shared__ float tile[32][33];
  const int z = blockIdx.z;
  int K, N;
  const float* s;
  u16* d;
  if (z < 8) {
    K = 1024; N = 512;
    s = (z < 2) ? (sW1 + (size_t)z * K * N) : (pW1 + (size_t)(z - 2) * K * N);
    d = w1t + (size_t)z * K * N;
  } else {
    K = 512; N = 256;
    const int e = z - 8;
    if (blockIdx.x >= 8 || blockIdx.y >= 16) return;
    s = (e < 2) ? (sW2 + (size_t)e * K * N) : (pW2 + (size_t)(e - 2) * K * N);
    d = w2t + (size_t)e * K * N;
  }
  int n0 = blockIdx.x * 32, k0 = blockIdx.y * 32;
  int tx = threadIdx.x, ty = threadIdx.y;
#pragma unroll
  for (int i = ty; i < 32; i += 8)
    tile[i][tx] = s[(size_t)(k0 + i) * N + n0 + tx];
  __syncthreads();
#pragma unroll
  for (int i = ty; i < 32; i += 8)
    d[(size_t)(n0 + i) * K + k0 + tx] = f2bf(tile[tx][i]);
}

// ---- gates + cast: gts = softmax(x @ gate_W + gate_b); xb = bf16(x) ----
__global__ __launch_bounds__(256) void gates_cast_kernel(
    const float* __restrict__ x, const float* __restrict__ gW,
    const float* __restrict__ gb, float* __restrict__ gates,
    u16* __restrict__ xb) {
  __shared__ float gw[12][1024];
  const int tid = threadIdx.x;
  for (int i = tid; i < 12 * 1024; i += 256) {
    int tg = i >> 10, k = i & 1023;
    gw[tg][k] = gW[(size_t)(tg >> 2) * 4096 + (size_t)k * 4 + (tg & 3)];
  }
  __syncthreads();
  const int wid = tid >> 6, lane = tid & 63;
  const size_t b = (size_t)blockIdx.x * 4 + wid;
  const float* xr = x + b * 1024;
  u16* xbr = xb + b * 1024;
  float acc[12] = {};
  for (int kk = 0; kk < 16; ++kk) {
    float xv = xr[kk * 64 + lane];
    xbr[kk * 64 + lane] = f2bf(xv);
#pragma unroll
    for (int t = 0; t < 12; ++t) acc[t] += xv * gw[t][kk * 64 + lane];
  }
#pragma unroll
  for (int off = 32; off >= 1; off >>= 1)
#pragma unroll
    for (int t = 0; t < 12; ++t) acc[t] += __shfl_xor(acc[t], off);
  if (lane == 0) {
    float* gr = gates + b * 12;
#pragma unroll
    for (int t = 0; t < 3; ++t) {
      float l0 = acc[t * 4 + 0] + gb[t * 4 + 0];
      float l1 = acc[t * 4 + 1] + gb[t * 4 + 1];
      float l2 = acc[t * 4 + 2] + gb[t * 4 + 2];
      float l3 = acc[t * 4 + 3] + gb[t * 4 + 3];
      float mx = fmaxf(fmaxf(l0, l1), fmaxf(l2, l3));
      float e0 = __expf(l0 - mx), e1 = __expf(l1 - mx);
      float e2 = __expf(l2 - mx), e3 = __expf(l3 - mx);
      float inv = 1.f / (e0 + e1 + e2 + e3);
      gr[t * 4 + 0] = e0 * inv; gr[t * 4 + 1] = e1 * inv;
      gr[t * 4 + 2] = e2 * inv; gr[t * 4 + 3] = e3 * inv;
    }
  }
}

// ===== 128x256 MFMA GEMM, BK=32, 3-slot LDS ring, 2 blocks/CU (R5-proven) =====
// C[e] = relu(A[e] @ Bt[e]^T + bias[e]),  A:[M][K] bf16, Bt:[e][N][K] bf16.
// 256 threads = 4 waves (1M x 4N), per-wave 128x64 output, acc[8][4] (128 AGPR).
// LDS: 3 slots x 24KB = 72KB -> 2 blocks/CU; two independent 4-wave barrier
// domains per CU (m114 overlap). Stage tile t+2 during t; steady vmcnt(6);
// exact tail: t=NT-2 -> vmcnt(0), t=NT-1 -> none.
// T2 swizzle: 16B-slot s' = s ^ ((row>>1)&3) on BOTH stage-source and ds_read.
__global__ __launch_bounds__(256, 2) void gemm_ring3(
    const u16* __restrict__ A, size_t strideAe,
    const u16* __restrict__ Bt,
    const float* __restrict__ bias_sh, const float* __restrict__ bias_sp,
    u16* __restrict__ C, int M, int N, int K, int ntn_sh) {
  __shared__ __align__(16) u16 lds[3 * 12288];  // 72 KB
  const int tid = threadIdx.x;
  const int wid = tid >> 6, lane = tid & 63;
  const int fr = lane & 15, fq = lane >> 4;
  const int wc = wid;

  const int bid = blockIdx.x;
  const int e = bid & 7;
  const int r = bid >> 3;
  const int mtile = r >> ntn_sh;
  const int ntile = r & ((1 << ntn_sh) - 1);
  const int m0 = mtile * 128, n0 = ntile * 256;

  const u16* Ae = A + (size_t)e * strideAe;
  const u16* Be = Bt + (size_t)e * (size_t)N * K;
  const int NT = K >> 5;

  const u16* pA[2];
  const u16* pB[4];
#pragma unroll
  for (int p = 0; p < 2; ++p) {
    int c = p * 256 + tid, row = c >> 2, sl = (c & 3) ^ ((row >> 1) & 3);
    pA[p] = Ae + (size_t)(m0 + row) * K + sl * 8;
  }
#pragma unroll
  for (int p = 0; p < 4; ++p) {
    int c = p * 256 + tid, row = c >> 2, sl = (c & 3) ^ ((row >> 1) & 3);
    pB[p] = Be + (size_t)(n0 + row) * K + sl * 8;
  }
  const int wdst = wid * 512;

  int offA[8], offB[4];
#pragma unroll
  for (int m = 0; m < 8; ++m) {
    int rr = m * 16 + fr;
    offA[m] = rr * 32 + ((fq ^ ((rr >> 1) & 3)) * 8);
  }
#pragma unroll
  for (int n = 0; n < 4; ++n) {
    int cg = wc * 64 + n * 16 + fr;
    offB[n] = 4096 + cg * 32 + ((fq ^ ((cg >> 1) & 3)) * 8);
  }

  f32x4 acc[8][4] = {};

#define STAGE(t, sb) do {                                             \
    gload16(pA[0] + (size_t)(t) * 32, &lds[(sb) + wdst]);             \
    gload16(pA[1] + (size_t)(t) * 32, &lds[(sb) + 2048 + wdst]);      \
    gload16(pB[0] + (size_t)(t) * 32, &lds[(sb) + 4096 + wdst]);      \
    gload16(pB[1] + (size_t)(t) * 32, &lds[(sb) + 6144 + wdst]);      \
    gload16(pB[2] + (size_t)(t) * 32, &lds[(sb) + 8192 + wdst]);      \
    gload16(pB[3] + (size_t)(t) * 32, &lds[(sb) + 10240 + wdst]); } while (0)

  STAGE(0, 0);
  STAGE(1, 12288);
  asm volatile("s_waitcnt vmcnt(6)");
  __builtin_amdgcn_s_barrier();
  __builtin_amdgcn_sched_barrier(0);

  int sb_cur = 0;
  for (int t = 0; t < NT; ++t) {
    const u16* sl = &lds[sb_cur];
    bf16x8 av[8], bv[4];
#pragma unroll
    for (int m = 0; m < 8; ++m) av[m] = *(const bf16x8*)&sl[offA[m]];
#pragma unroll
    for (int n = 0; n < 4; ++n) bv[n] = *(const bf16x8*)&sl[offB[n]];
    if (t + 2 < NT) {
      int sb_n2 = sb_cur + 2 * 12288;
      if (sb_n2 >= 36864) sb_n2 -= 36864;
      STAGE(t + 2, sb_n2);
    }
    __builtin_amdgcn_s_setprio(1);
#pragma unroll
    for (int m = 0; m < 8; ++m)
#pragma unroll
      for (int n = 0; n < 4; ++n)
        acc[m][n] = __builtin_amdgcn_mfma_f32_16x16x32_bf16(av[m], bv[n], acc[m][n], 0, 0, 0);
    __builtin_amdgcn_s_setprio(0);
    if (t + 2 < NT)      asm volatile("s_waitcnt vmcnt(6)");
    else if (t + 1 < NT) asm volatile("s_waitcnt vmcnt(0)");
    __builtin_amdgcn_s_barrier();
    __builtin_amdgcn_sched_barrier(0);
    sb_cur += 12288;
    if (sb_cur >= 36864) sb_cur = 0;
  }
#undef STAGE

  const float* bias = (e < ESH) ? (bias_sh + (size_t)e * N)
                                : (bias_sp + (size_t)(e - ESH) * N);
  u16* Ce = C + (size_t)e * (size_t)M * N;
  float bb[4];
#pragma unroll
  for (int n = 0; n < 4; ++n) bb[n] = bias[n0 + wc * 64 + n * 16 + fr];

#pragma unroll
  for (int m = 0; m < 8; ++m) {
#pragma unroll
    for (int n = 0; n < 4; ++n) {
      const int col = wc * 64 + n * 16 + fr;
      f32x4 a = acc[m][n];
#pragma unroll
      for (int rr = 0; rr < 4; ++rr) {
        float v = a[rr] + bb[n];
        v = v > 0.f ? v : 0.f;
        lds[(m * 16 + fq * 4 + rr) * 264 + col] = f2bf(v);
      }
    }
  }
  __builtin_amdgcn_s_barrier();
  const int cc = (tid & 31) * 8;
  const int rr8 = tid >> 5;
#pragma unroll
  for (int pass = 0; pass < 16; ++pass) {
    const int lr = pass * 8 + rr8;
    u16x8 vv = *(const u16x8*)&lds[lr * 264 + cc];
    *(u16x8*)&Ce[(size_t)(m0 + lr) * N + n0 + cc] = vv;
  }
}

// ---------------- combine: out[b][t][h] = sum_g gate[b][t][g] * Y2[slot][b][h] ----------------
__global__ __launch_bounds__(256) void combine_kernel(
    const u16* __restrict__ y2, const float* __restrict__ gates,
    float* __restrict__ out) {
  const int tid = threadIdx.x;
  const int rb = tid >> 5;            // row within block (8 rows/block)
  const int hc = (tid & 31) * 8;      // h chunk of 8
  const size_t b = (size_t)blockIdx.x * 8 + rb;
  const float* g = gates + b * 12;
  float acc0[8] = {}, acc1[8] = {}, acc2[8] = {};
#pragma unroll
  for (int e = 0; e < 8; ++e) {
    u16x8 v = *(const u16x8*)&y2[(size_t)e * B_SZ * H2_SZ + b * H2_SZ + hc];
    float f[8];
#pragma unroll
    for (int i = 0; i < 8; ++i) f[i] = bf2f(v[i]);
    if (e < 2) {
      float g0 = g[0 * 4 + e], g1 = g[1 * 4 + e], g2 = g[2 * 4 + e];
#pragma unroll
      for (int i = 0; i < 8; ++i) {
        acc0[i] += g0 * f[i]; acc1[i] += g1 * f[i]; acc2[i] += g2 * f[i];
      }
    } else {
      const int t = (e - 2) >> 1, gi = 2 + ((e - 2) & 1);
      float gv = g[t * 4 + gi];
      float* acc = (t == 0) ? acc0 : (t == 1) ? acc1 : acc2;
#pragma unroll
      for (int i = 0; i < 8; ++i) acc[i] += gv * f[i];
    }
  }
  float* o = out + b * (3 * 256);
  *(float4*)&o[0 * 256 + hc]     = make_float4(acc0[0], acc0[1], acc0[2], acc0[3]);
  *(float4*)&o[0 * 256 + hc + 4] = make_float4(acc0[4], acc0[5], acc0[6], acc0[7]);
  *(float4*)&o[1 * 256 + hc]     = make_float4(acc1[0], acc1[1], acc1[2], acc1[3]);
  *(float4*)&o[1 * 256 + hc + 4] = make_float4(acc1[4], acc1[5], acc1[6], acc1[7]);
  *(float4*)&o[2 * 256 + hc]     = make_float4(acc2[0], acc2[1], acc2[2], acc2[3]);
  *(float4*)&o[2 * 256 + hc + 4] = make_float4(acc2[4], acc2[5], acc2[6], acc2[7]);
}

extern "C" void kernel_launch(void* const* d_in, const int* in_sizes, int n_in,
                              void* d_out, int out_size, void* d_ws, size_t ws_size,
                              hipStream_t stream) {
  (void)in_sizes; (void)n_in; (void)out_size; (void)ws_size;
  const float* x   = (const float*)d_in[0];
  const float* sW1 = (const float*)d_in[1];
  const float* sb1 = (const float*)d_in[2];
  const float* sW2 = (const float*)d_in[3];
  const float* sb2 = (const float*)d_in[4];
  const float* pW1 = (const float*)d_in[5];
  const float* pb1 = (const float*)d_in[6];
  const float* pW2 = (const float*)d_in[7];
  const float* pb2 = (const float*)d_in[8];
  const float* gW  = (const float*)d_in[9];
  const float* gb  = (const float*)d_in[10];

  uint8_t* ws = (uint8_t*)d_ws;
  u16* xb    = (u16*)(ws);                        // 33,554,432 B
  u16* w1t   = (u16*)(ws + 33554432);             //  8,388,608 B  [8][512][1024]
  u16* w2t   = (u16*)(ws + 41943040);             //  2,097,152 B  [8][256][512]
  u16* y1    = (u16*)(ws + 44040192);             // 134,217,728 B [8][B][512]
  u16* y2    = (u16*)(ws + 178257920);            // 67,108,864 B  [8][B][256]
  float* gts = (float*)(ws + 245366784);          //    786,432 B  [B][3][4]

  // 1) all weight transposes in one launch (W1: z=0..7, W2: z=8..15)
  transpose_cast_all<<<dim3(16, 32, 16), dim3(32, 8), 0, stream>>>(
      sW1, pW1, sW2, pW2, w1t, w2t);

  // 2) gates + x-cast fused
  gates_cast_kernel<<<B_SZ / 4, 256, 0, stream>>>(x, gW, gb, gts, xb);

  // 3) layer-1 GEMM: y1[e] = relu(xb @ w1t[e]^T + b1[e])   grid 128*2*8 = 2048
  gemm_ring3<<<(B_SZ / 128) * (512 / 256) * NE, 256, 0, stream>>>(
      xb, 0, w1t, sb1, pb1, y1, B_SZ, 512, 1024, 1);

  // 4) layer-2 GEMM: y2[e] = relu(y1[e] @ w2t[e]^T + b2[e])  grid 128*1*8 = 1024
  gemm_ring3<<<(B_SZ / 128) * (256 / 256) * NE, 256, 0, stream>>>(
      y1, (size_t)B_SZ * 512, w2t, sb2, pb2, y2, B_SZ, 256, 512, 0);

  // 5) combine with gates -> out [B][3][256] fp32
  combine_kernel<<<B_SZ / 8, 256, 0, stream>>>(y2, gts, (float*)d_out);
}